// Round 10
// baseline (362.588 us; speedup 1.0000x reference)
//
#include <hip/hip_runtime.h>
#include <hip/hip_bf16.h>
#include <math.h>

typedef __hip_bfloat16 bf16;
typedef __attribute__((ext_vector_type(8))) short short8;
typedef __attribute__((ext_vector_type(4))) short short4v;
typedef __attribute__((ext_vector_type(4))) float floatx4;

#define D_MODEL 1024
#define SEQ     2048
#define BATCH   2
#define NHEAD   16
#define HDIM    64
#define FFDIM   4096
#define ROWS    (BATCH*SEQ)   // 4096 token rows

__device__ __forceinline__ void stv(bf16* p, float v)  { *p = __float2bfloat16(v); }
__device__ __forceinline__ void stv(float* p, float v) { *p = v; }

__device__ __forceinline__ void load_lds16(const bf16* g, bf16* l) {
  __builtin_amdgcn_global_load_lds((const __attribute__((address_space(1))) void*)g,
                                   (__attribute__((address_space(3))) void*)l, 16, 0, 0);
}

// fast GELU: x * sigmoid(x*(c0 + c1*x^2)) == tanh-form GELU; max |err| vs exact ~4e-4
__device__ __forceinline__ float gelu_fast(float x) {
  float z = x * (1.5957691f + 0.07135481f * x * x);
  return x * __builtin_amdgcn_rcpf(1.0f + __expf(-z));
}

// ---------------- LayerNorm: one 256-thread block per row of 1024 ----------------
template<typename IN_T>
__global__ void ln_kernel(const IN_T* __restrict__ x, const float* __restrict__ g,
                          const float* __restrict__ beta, bf16* __restrict__ out) {
  const int row = blockIdx.x;
  const int tid = threadIdx.x;
  __shared__ float red[8];
  const IN_T* xr = x + (size_t)row * D_MODEL;
  float v[4], s = 0.f, ss = 0.f;
#pragma unroll
  for (int i = 0; i < 4; i++) {
    float val = (float)xr[tid + i * 256];
    v[i] = val; s += val; ss += val * val;
  }
#pragma unroll
  for (int off = 32; off > 0; off >>= 1) {
    s  += __shfl_down(s, off);
    ss += __shfl_down(ss, off);
  }
  if ((tid & 63) == 0) { red[tid >> 6] = s; red[4 + (tid >> 6)] = ss; }
  __syncthreads();
  s  = red[0] + red[1] + red[2] + red[3];
  ss = red[4] + red[5] + red[6] + red[7];
  const float mu  = s * (1.0f / D_MODEL);
  const float var = ss * (1.0f / D_MODEL) - mu * mu;
  const float rs  = rsqrtf(var + 1e-5f);
  bf16* orow = out + (size_t)row * D_MODEL;
#pragma unroll
  for (int i = 0; i < 4; i++) {
    int c = tid + i * 256;
    stv(orow + c, (v[i] - mu) * rs * g[c] + beta[c]);
  }
}

// -------- W[K][N] f32 -> Wt[N][K] bf16, two jobs batched in one dispatch --------
__device__ __forceinline__ void convert_tile(const float* W, bf16* Wt,
                                             int K, int N, int n0, int k0, int tid) {
  __shared__ float tile[64][65];
  const int r = tid >> 2, c0 = (tid & 3) * 16;
#pragma unroll
  for (int j = 0; j < 16; j += 4) {
    float4 v = *(const float4*)&W[(size_t)(k0 + r) * N + n0 + c0 + j];
    tile[r][c0 + j]     = v.x; tile[r][c0 + j + 1] = v.y;
    tile[r][c0 + j + 2] = v.z; tile[r][c0 + j + 3] = v.w;
  }
  __syncthreads();
  bf16 ov[16];
#pragma unroll
  for (int j = 0; j < 16; j++) ov[j] = __float2bfloat16(tile[c0 + j][r]);
  *(short8*)&Wt[(size_t)(n0 + r) * K + k0 + c0]     = *(const short8*)&ov[0];
  *(short8*)&Wt[(size_t)(n0 + r) * K + k0 + c0 + 8] = *(const short8*)&ov[8];
}

__global__ __launch_bounds__(256) void convert_w2(
    const float* __restrict__ W0, bf16* __restrict__ Wt0, int K0, int N0, int tiles0,
    const float* __restrict__ W1, bf16* __restrict__ Wt1, int K1, int N1) {
  int bid = blockIdx.x;
  const int tid = threadIdx.x;
  if (bid < tiles0) {
    const int nt = N0 >> 6;
    convert_tile(W0, Wt0, K0, N0, (bid % nt) * 64, (bid / nt) * 64, tid);
  } else {
    bid -= tiles0;
    const int nt = N1 >> 6;
    convert_tile(W1, Wt1, K1, N1, (bid % nt) * 64, (bid / nt) * 64, tid);
  }
}

// ------- MFMA GEMM: C[M,N] = act(A[M,K] @ Bt[N,K]^T + bias) (+res), tile TMxTN --
// 1D grid, XCD-clustered swizzle. VOUT: blocks with n0>=2048 write V^T to vout
// ([n-2048][m], b64 column stores) instead of C — fuses the V transpose into the
// qkv GEMM epilogue.
template<int ACT, bool HAS_RES, int TM, int TN, bool VOUT, typename OUT_T>
__global__ __launch_bounds__(256) void gemm_mfma(
    const bf16* __restrict__ A, const bf16* __restrict__ Bt,
    const float* __restrict__ bias, const float* __restrict__ res,
    OUT_T* __restrict__ C, bf16* __restrict__ vout, int M, int N, int K, int NTI) {
  constexpr int MT = (TN == 128) ? 4 : (TM == 128 ? 2 : 1);
  __shared__ __align__(16) bf16 As[TM][64];
  __shared__ __align__(16) bf16 Bs[TN][64];
  const int tid = threadIdx.x;
  const int w = tid >> 6, lane = tid & 63;
  const int quad = lane >> 4, l16 = lane & 15;
  const int wm = (TN == 128) ? (w >> 1) : w;
  const int wn = (TN == 128) ? (w & 1) : 0;
  const int wave_m_off = wm * (MT * 16);
  const int bid = blockIdx.x;
  const int n_idx = (bid >> 3) % NTI;
  const int m_idx = ((bid >> 3) / NTI) * 8 + (bid & 7);
  const int m0 = m_idx * TM, n0 = n_idx * TN;
  const int rb = lane >> 3, cb = lane & 7;
  const int csw = cb ^ rb;

  const bf16* Ag = A  + (size_t)(m0 + (tid >> 3)) * K + csw * 8;
  const bf16* Bg = Bt + (size_t)(n0 + (tid >> 3)) * K + csw * 8;

  floatx4 acc[MT][4];
#pragma unroll
  for (int i = 0; i < MT; i++)
#pragma unroll
    for (int j = 0; j < 4; j++) acc[i][j] = (floatx4){0.f, 0.f, 0.f, 0.f};

  const int sw = l16 & 7;
  for (int k0 = 0; k0 < K; k0 += 64) {
    __syncthreads();
#pragma unroll
    for (int j = 0; j < TM / 32; j++)
      load_lds16(Ag + k0 + (size_t)j * 32 * K, &As[j * 32 + (tid >> 3)][0]);
#pragma unroll
    for (int j = 0; j < TN / 32; j++)
      load_lds16(Bg + k0 + (size_t)j * 32 * K, &Bs[j * 32 + (tid >> 3)][0]);
    __syncthreads();
    short8 af[MT][2], bfr[4][2];
#pragma unroll
    for (int t = 0; t < MT; t++)
#pragma unroll
      for (int hh = 0; hh < 2; hh++) {
        int cc = ((quad + hh * 4) ^ sw) * 8;
        af[t][hh] = *(const short8*)&As[wave_m_off + t * 16 + l16][cc];
      }
#pragma unroll
    for (int t = 0; t < 4; t++)
#pragma unroll
      for (int hh = 0; hh < 2; hh++) {
        int cc = ((quad + hh * 4) ^ sw) * 8;
        bfr[t][hh] = *(const short8*)&Bs[wn * 64 + t * 16 + l16][cc];
      }
#pragma unroll
    for (int mt = 0; mt < MT; mt++)
#pragma unroll
      for (int nt = 0; nt < 4; nt++) {
        acc[mt][nt] = __builtin_amdgcn_mfma_f32_16x16x32_bf16(af[mt][0], bfr[nt][0], acc[mt][nt], 0, 0, 0);
        acc[mt][nt] = __builtin_amdgcn_mfma_f32_16x16x32_bf16(af[mt][1], bfr[nt][1], acc[mt][nt], 0, 0, 0);
      }
  }

  const int mbase = m0 + wave_m_off + quad * 4;
  const int nbase = n0 + wn * 64 + l16;
  float bv[4];
#pragma unroll
  for (int nt = 0; nt < 4; nt++) bv[nt] = bias[nbase + nt * 16];

  if (VOUT && n0 >= 2048) {
    // V^T epilogue: vout[(n-2048)*M + m], 4 consecutive m per lane -> b64 store
#pragma unroll
    for (int mt = 0; mt < MT; mt++) {
#pragma unroll
      for (int nt = 0; nt < 4; nt++) {
        const size_t col = (size_t)(nbase + nt * 16 - 2048);
        bf16 ov[4];
#pragma unroll
        for (int r = 0; r < 4; r++) ov[r] = __float2bfloat16(acc[mt][nt][r] + bv[nt]);
        *(short4v*)&vout[col * M + mbase + mt * 16] = *(const short4v*)ov;
      }
    }
    return;
  }

#pragma unroll
  for (int mt = 0; mt < MT; mt++) {
#pragma unroll
    for (int r = 0; r < 4; r++) {
      const int m = mbase + mt * 16 + r;
#pragma unroll
      for (int nt = 0; nt < 4; nt++) {
        const int n = nbase + nt * 16;
        float val = acc[mt][nt][r] + bv[nt];
        if (ACT == 1) val = gelu_fast(val);
        if (HAS_RES) val += res[(size_t)m * N + n];
        stv(&C[(size_t)m * N + n], val);
      }
    }
  }
}

// ---------------- Flash attention, transposed form, 128 q-rows/block ----------------
// 4 waves x 32 q (two 16-q B-frags per wave): each Ks/Vs b128 read feeds 2 MFMAs.
__global__ __launch_bounds__(256) void attn_mfma(const bf16* __restrict__ qkv,
                                                 const bf16* __restrict__ vT,
                                                 bf16* __restrict__ y) {
  const int qt = blockIdx.x, h = blockIdx.y, b = blockIdx.z;
  const int tid  = threadIdx.x;
  const int wave = tid >> 6, lane = tid & 63;
  const int quad = lane >> 4, l16 = lane & 15;
  const int sw8  = l16 & 7;

  __shared__ __align__(16) bf16 Ks[64 * 64];
  __shared__ __align__(16) bf16 Vs[64 * 64];
  __shared__ __align__(16) bf16 Ps[4][2][16 * 64];

  const size_t base = (size_t)b * SEQ * 3072;
  const int q0 = qt * 128 + wave * 32;

  // Q fragments (B-operand), two 16-q groups, pre-scaled by 1/8 (exact in bf16)
  short8 qb[2][2];
#pragma unroll
  for (int u = 0; u < 2; u++) {
    const bf16* qrow = qkv + base + (size_t)(q0 + u * 16 + l16) * 3072 + h * HDIM;
    qb[u][0] = *(const short8*)(qrow + quad * 8);
    qb[u][1] = *(const short8*)(qrow + 32 + quad * 8);
    bf16* p0 = (bf16*)&qb[u][0]; bf16* p1 = (bf16*)&qb[u][1];
#pragma unroll
    for (int j = 0; j < 8; j++) {
      p0[j] = __float2bfloat16(__bfloat162float(p0[j]) * 0.125f);
      p1[j] = __float2bfloat16(__bfloat162float(p1[j]) * 0.125f);
    }
  }

  floatx4 O[2][4];
#pragma unroll
  for (int u = 0; u < 2; u++)
#pragma unroll
    for (int c = 0; c < 4; c++) O[u][c] = (floatx4){0.f, 0.f, 0.f, 0.f};
  float lsum[2] = {0.f, 0.f};

  const int skey = tid >> 3, sc = tid & 7;
  const int gcol = (sc ^ (skey & 7)) * 8;
  const bf16* kg = qkv + base + D_MODEL + h * HDIM;
  const bf16* vg = vT + (size_t)(h * HDIM) * (size_t)ROWS + b * SEQ;

  for (int kt = 0; kt < SEQ; kt += 64) {
    __syncthreads();
    load_lds16(kg + (size_t)(kt + skey) * 3072 + gcol,      &Ks[tid * 8]);
    load_lds16(kg + (size_t)(kt + skey + 32) * 3072 + gcol, &Ks[(tid + 256) * 8]);
    load_lds16(vg + (size_t)skey * ROWS + kt + gcol,        &Vs[tid * 8]);
    load_lds16(vg + (size_t)(skey + 32) * ROWS + kt + gcol, &Vs[(tid + 256) * 8]);
    __syncthreads();

    // S^T = K @ Q^T, exp, store P^T — K-frags shared across both q-groups
#pragma unroll
    for (int g = 0; g < 4; g++) {
      const short8 ka0 = *(const short8*)&Ks[(g * 16 + l16) * 64 + ((quad    ) ^ sw8) * 8];
      const short8 ka1 = *(const short8*)&Ks[(g * 16 + l16) * 64 + ((quad + 4) ^ sw8) * 8];
      const int chunk = 2 * g + (quad >> 1);
#pragma unroll
      for (int u = 0; u < 2; u++) {
        floatx4 S = (floatx4){0.f, 0.f, 0.f, 0.f};
        S = __builtin_amdgcn_mfma_f32_16x16x32_bf16(ka0, qb[u][0], S, 0, 0, 0);
        S = __builtin_amdgcn_mfma_f32_16x16x32_bf16(ka1, qb[u][1], S, 0, 0, 0);
        float p[4];
#pragma unroll
        for (int r = 0; r < 4; r++) { p[r] = __expf(S[r]); lsum[u] += p[r]; }
        bf16 pb[4];
#pragma unroll
        for (int r = 0; r < 4; r++) pb[r] = __float2bfloat16(p[r]);
        *(short4v*)&Ps[wave][u][l16 * 64 + (chunk ^ sw8) * 8 + (quad & 1) * 4] =
            *(const short4v*)pb;
      }
    }

    short8 pb0[2], pb1[2];
#pragma unroll
    for (int u = 0; u < 2; u++) {
      pb0[u] = *(const short8*)&Ps[wave][u][l16 * 64 + ((quad    ) ^ sw8) * 8];
      pb1[u] = *(const short8*)&Ps[wave][u][l16 * 64 + ((quad + 4) ^ sw8) * 8];
    }

    // O^T += V^T @ P^T — V-frags shared across both q-groups
#pragma unroll
    for (int c = 0; c < 4; c++) {
      const short8 va0 = *(const short8*)&Vs[(c * 16 + l16) * 64 + ((quad    ) ^ sw8) * 8];
      const short8 va1 = *(const short8*)&Vs[(c * 16 + l16) * 64 + ((quad + 4) ^ sw8) * 8];
#pragma unroll
      for (int u = 0; u < 2; u++) {
        O[u][c] = __builtin_amdgcn_mfma_f32_16x16x32_bf16(va0, pb0[u], O[u][c], 0, 0, 0);
        O[u][c] = __builtin_amdgcn_mfma_f32_16x16x32_bf16(va1, pb1[u], O[u][c], 0, 0, 0);
      }
    }
  }

#pragma unroll
  for (int u = 0; u < 2; u++) {
    float ls = lsum[u];
    ls += __shfl_xor(ls, 16);
    ls += __shfl_xor(ls, 32);
    const float inv = 1.0f / ls;
    bf16* yrow = y + (size_t)(b * SEQ + q0 + u * 16 + l16) * D_MODEL + h * HDIM + quad * 4;
#pragma unroll
    for (int c = 0; c < 4; c++) {
      bf16 ov[4];
#pragma unroll
      for (int r = 0; r < 4; r++) ov[r] = __float2bfloat16(O[u][c][r] * inv);
      *(short4v*)(yrow + c * 16) = *(const short4v*)ov;
    }
  }
}

extern "C" void kernel_launch(void* const* d_in, const int* in_sizes, int n_in,
                              void* d_out, int out_size, void* d_ws, size_t ws_size,
                              hipStream_t stream) {
  const float* x      = (const float*)d_in[0];
  const float* ln1_g  = (const float*)d_in[1];
  const float* ln1_b  = (const float*)d_in[2];
  const float* ln2_g  = (const float*)d_in[3];
  const float* ln2_b  = (const float*)d_in[4];
  const float* w_qkv  = (const float*)d_in[5];
  const float* b_qkv  = (const float*)d_in[6];
  const float* w_proj = (const float*)d_in[7];
  const float* b_proj = (const float*)d_in[8];
  const float* w_fc1  = (const float*)d_in[9];
  const float* b_fc1  = (const float*)d_in[10];
  const float* w_fc2  = (const float*)d_in[11];
  const float* b_fc2  = (const float*)d_in[12];
  float* out = (float*)d_out;

  // Workspace map (88 MiB high-water):
  //   [ 0, 8M)  h        [ 8,32M) qkv (Q,K; V cols land in vT)
  //   [ 8,16M)  wt_fc1 (overlay, post-attn)   [16,24M) wt_fc2 (overlay, post-attn)
  //   [32,40M)  y        [40,56M) x1 (f32)    [56,88M) ffh
  //   [56,62M)  wt_qkv   [62,64M) wt_proj     [64,72M) vT (dead before ffh written)
  char* ws = (char*)d_ws;
  bf16*  h       = (bf16*)(ws);
  bf16*  qkv     = (bf16*)(ws + (8u  << 20));
  bf16*  wt_fc1  = (bf16*)(ws + (8u  << 20));
  bf16*  wt_fc2  = (bf16*)(ws + (16u << 20));
  bf16*  y       = (bf16*)(ws + (32u << 20));
  float* x1      = (float*)(ws + (40u << 20));
  bf16*  ffh     = (bf16*)(ws + (56u << 20));
  bf16*  wt_qkv  = (bf16*)(ws + (56u << 20));
  bf16*  wt_proj = (bf16*)(ws + (62u << 20));
  bf16*  vT      = (bf16*)(ws + (64u << 20));

  // qkv + proj weight converts (one dispatch)
  convert_w2<<<768 + 256, 256, 0, stream>>>(w_qkv, wt_qkv, 1024, 3072, 768,
                                            w_proj, wt_proj, 1024, 1024);
  // 1. h = LN1(x)
  ln_kernel<float><<<ROWS, 256, 0, stream>>>(x, ln1_g, ln1_b, h);
  // 2. qkv = h @ w_qkv + b_qkv; V third written transposed to vT
  gemm_mfma<0, false, 128, 128, true, bf16><<<768, 256, 0, stream>>>(
      h, wt_qkv, b_qkv, nullptr, qkv, vT, ROWS, 3072, D_MODEL, 24);
  // 3. y = softmax(q k^T / 8) v   (128 q-rows/block)
  attn_mfma<<<dim3(SEQ / 128, NHEAD, BATCH), 256, 0, stream>>>(qkv, vT, y);
  // fc1 + fc2 weight converts (one dispatch; must follow attn: overlays qkv)
  convert_w2<<<1024 + 1024, 256, 0, stream>>>(w_fc1, wt_fc1, 1024, 4096, 1024,
                                              w_fc2, wt_fc2, 4096, 1024);
  // 4. x1 = x + y @ w_proj + b_proj   (64x64 tiles, 1024 blocks)
  gemm_mfma<0, true, 64, 64, false, float><<<1024, 256, 0, stream>>>(
      y, wt_proj, b_proj, x, x1, nullptr, ROWS, D_MODEL, D_MODEL, 16);
  // 5. h = LN2(x1)
  ln_kernel<float><<<ROWS, 256, 0, stream>>>(x1, ln2_g, ln2_b, h);
  // 6. ffh = gelu(h @ w_fc1 + b_fc1)   (128x128, 1024 blocks)
  gemm_mfma<1, false, 128, 128, false, bf16><<<1024, 256, 0, stream>>>(
      h, wt_fc1, b_fc1, nullptr, ffh, nullptr, ROWS, FFDIM, D_MODEL, 32);
  // 7. out = x1 + ffh @ w_fc2 + b_fc2   (64x64 tiles, 1024 blocks)
  gemm_mfma<0, true, 64, 64, false, float><<<1024, 256, 0, stream>>>(
      ffh, wt_fc2, b_fc2, x1, out, nullptr, ROWS, D_MODEL, FFDIM, 16);
}

// Round 11
// 353.222 us; speedup vs baseline: 1.0265x; 1.0265x over previous
//
#include <hip/hip_runtime.h>
#include <hip/hip_bf16.h>
#include <math.h>

typedef __hip_bfloat16 bf16;
typedef __attribute__((ext_vector_type(8))) short short8;
typedef __attribute__((ext_vector_type(4))) short short4v;
typedef __attribute__((ext_vector_type(4))) float floatx4;

#define D_MODEL 1024
#define SEQ     2048
#define BATCH   2
#define NHEAD   16
#define HDIM    64
#define FFDIM   4096
#define ROWS    (BATCH*SEQ)   // 4096 token rows

#if __has_builtin(__builtin_amdgcn_exp2f)
#define EXP2(x) __builtin_amdgcn_exp2f(x)
#else
#define EXP2(x) exp2f(x)
#endif

__device__ __forceinline__ void stv(bf16* p, float v)  { *p = __float2bfloat16(v); }
__device__ __forceinline__ void stv(float* p, float v) { *p = v; }

__device__ __forceinline__ void load_lds16(const bf16* g, bf16* l) {
  __builtin_amdgcn_global_load_lds((const __attribute__((address_space(1))) void*)g,
                                   (__attribute__((address_space(3))) void*)l, 16, 0, 0);
}

// fast GELU: x * sigmoid(x*(c0 + c1*x^2)) == tanh-form GELU; max |err| vs exact ~4e-4
__device__ __forceinline__ float gelu_fast(float x) {
  float z = x * (1.5957691f + 0.07135481f * x * x);
  return x * __builtin_amdgcn_rcpf(1.0f + __expf(-z));
}

// ---------------- LayerNorm: one 256-thread block per row of 1024 ----------------
template<typename IN_T>
__global__ void ln_kernel(const IN_T* __restrict__ x, const float* __restrict__ g,
                          const float* __restrict__ beta, bf16* __restrict__ out) {
  const int row = blockIdx.x;
  const int tid = threadIdx.x;
  __shared__ float red[8];
  const IN_T* xr = x + (size_t)row * D_MODEL;
  float v[4], s = 0.f, ss = 0.f;
#pragma unroll
  for (int i = 0; i < 4; i++) {
    float val = (float)xr[tid + i * 256];
    v[i] = val; s += val; ss += val * val;
  }
#pragma unroll
  for (int off = 32; off > 0; off >>= 1) {
    s  += __shfl_down(s, off);
    ss += __shfl_down(ss, off);
  }
  if ((tid & 63) == 0) { red[tid >> 6] = s; red[4 + (tid >> 6)] = ss; }
  __syncthreads();
  s  = red[0] + red[1] + red[2] + red[3];
  ss = red[4] + red[5] + red[6] + red[7];
  const float mu  = s * (1.0f / D_MODEL);
  const float var = ss * (1.0f / D_MODEL) - mu * mu;
  const float rs  = rsqrtf(var + 1e-5f);
  bf16* orow = out + (size_t)row * D_MODEL;
#pragma unroll
  for (int i = 0; i < 4; i++) {
    int c = tid + i * 256;
    stv(orow + c, (v[i] - mu) * rs * g[c] + beta[c]);
  }
}

// -------- W[K][N] f32 -> Wt[N][K] bf16, two jobs batched in one dispatch --------
__device__ __forceinline__ void convert_tile(const float* W, bf16* Wt,
                                             int K, int N, int n0, int k0, int tid) {
  __shared__ float tile[64][65];
  const int r = tid >> 2, c0 = (tid & 3) * 16;
#pragma unroll
  for (int j = 0; j < 16; j += 4) {
    float4 v = *(const float4*)&W[(size_t)(k0 + r) * N + n0 + c0 + j];
    tile[r][c0 + j]     = v.x; tile[r][c0 + j + 1] = v.y;
    tile[r][c0 + j + 2] = v.z; tile[r][c0 + j + 3] = v.w;
  }
  __syncthreads();
  bf16 ov[16];
#pragma unroll
  for (int j = 0; j < 16; j++) ov[j] = __float2bfloat16(tile[c0 + j][r]);
  *(short8*)&Wt[(size_t)(n0 + r) * K + k0 + c0]     = *(const short8*)&ov[0];
  *(short8*)&Wt[(size_t)(n0 + r) * K + k0 + c0 + 8] = *(const short8*)&ov[8];
}

__global__ __launch_bounds__(256) void convert_w2(
    const float* __restrict__ W0, bf16* __restrict__ Wt0, int K0, int N0, int tiles0,
    const float* __restrict__ W1, bf16* __restrict__ Wt1, int K1, int N1) {
  int bid = blockIdx.x;
  const int tid = threadIdx.x;
  if (bid < tiles0) {
    const int nt = N0 >> 6;
    convert_tile(W0, Wt0, K0, N0, (bid % nt) * 64, (bid / nt) * 64, tid);
  } else {
    bid -= tiles0;
    const int nt = N1 >> 6;
    convert_tile(W1, Wt1, K1, N1, (bid % nt) * 64, (bid / nt) * 64, tid);
  }
}

// ------------- V-transpose: vT[h*64+d][b*2048+t] = qkv[b*2048+t][2048+h*64+d] ----
__global__ __launch_bounds__(256) void v_transpose(const bf16* __restrict__ qkv,
                                                   bf16* __restrict__ vT) {
  __shared__ bf16 tile[64][72];
  const int m0 = blockIdx.x * 64;
  const int d0 = blockIdx.y * 64;
  const int tid = threadIdx.x;
  const int r = tid >> 2, c0 = (tid & 3) * 16;
  *(short8*)&tile[r][c0]     = *(const short8*)&qkv[(size_t)(m0 + r) * 3072 + 2048 + d0 + c0];
  *(short8*)&tile[r][c0 + 8] = *(const short8*)&qkv[(size_t)(m0 + r) * 3072 + 2048 + d0 + c0 + 8];
  __syncthreads();
  bf16 ov[16];
#pragma unroll
  for (int j = 0; j < 16; j++) ov[j] = tile[c0 + j][r];
  *(short8*)&vT[(size_t)(d0 + r) * (size_t)ROWS + m0 + c0]     = *(const short8*)&ov[0];
  *(short8*)&vT[(size_t)(d0 + r) * (size_t)ROWS + m0 + c0 + 8] = *(const short8*)&ov[8];
}

// ------- MFMA GEMM: C[M,N] = act(A[M,K] @ Bt[N,K]^T + bias) (+res), tile TMxTN --
// 1D grid, XCD-clustered swizzle: blocks sharing an A-panel land on one XCD.
template<int ACT, bool HAS_RES, int TM, int TN, typename OUT_T>
__global__ __launch_bounds__(256) void gemm_mfma(
    const bf16* __restrict__ A, const bf16* __restrict__ Bt,
    const float* __restrict__ bias, const float* __restrict__ res,
    OUT_T* __restrict__ C, int M, int N, int K, int NTI) {
  constexpr int MT = (TN == 128) ? 4 : (TM == 128 ? 2 : 1);
  __shared__ __align__(16) bf16 As[TM][64];
  __shared__ __align__(16) bf16 Bs[TN][64];
  const int tid = threadIdx.x;
  const int w = tid >> 6, lane = tid & 63;
  const int quad = lane >> 4, l16 = lane & 15;
  const int wm = (TN == 128) ? (w >> 1) : w;
  const int wn = (TN == 128) ? (w & 1) : 0;
  const int wave_m_off = wm * (MT * 16);
  const int bid = blockIdx.x;
  const int n_idx = (bid >> 3) % NTI;
  const int m_idx = ((bid >> 3) / NTI) * 8 + (bid & 7);
  const int m0 = m_idx * TM, n0 = n_idx * TN;
  const int rb = lane >> 3, cb = lane & 7;
  const int csw = cb ^ rb;

  const bf16* Ag = A  + (size_t)(m0 + (tid >> 3)) * K + csw * 8;
  const bf16* Bg = Bt + (size_t)(n0 + (tid >> 3)) * K + csw * 8;

  floatx4 acc[MT][4];
#pragma unroll
  for (int i = 0; i < MT; i++)
#pragma unroll
    for (int j = 0; j < 4; j++) acc[i][j] = (floatx4){0.f, 0.f, 0.f, 0.f};

  const int sw = l16 & 7;
  for (int k0 = 0; k0 < K; k0 += 64) {
    __syncthreads();
#pragma unroll
    for (int j = 0; j < TM / 32; j++)
      load_lds16(Ag + k0 + (size_t)j * 32 * K, &As[j * 32 + (tid >> 3)][0]);
#pragma unroll
    for (int j = 0; j < TN / 32; j++)
      load_lds16(Bg + k0 + (size_t)j * 32 * K, &Bs[j * 32 + (tid >> 3)][0]);
    __syncthreads();
    short8 af[MT][2], bfr[4][2];
#pragma unroll
    for (int t = 0; t < MT; t++)
#pragma unroll
      for (int hh = 0; hh < 2; hh++) {
        int cc = ((quad + hh * 4) ^ sw) * 8;
        af[t][hh] = *(const short8*)&As[wave_m_off + t * 16 + l16][cc];
      }
#pragma unroll
    for (int t = 0; t < 4; t++)
#pragma unroll
      for (int hh = 0; hh < 2; hh++) {
        int cc = ((quad + hh * 4) ^ sw) * 8;
        bfr[t][hh] = *(const short8*)&Bs[wn * 64 + t * 16 + l16][cc];
      }
#pragma unroll
    for (int mt = 0; mt < MT; mt++)
#pragma unroll
      for (int nt = 0; nt < 4; nt++) {
        acc[mt][nt] = __builtin_amdgcn_mfma_f32_16x16x32_bf16(af[mt][0], bfr[nt][0], acc[mt][nt], 0, 0, 0);
        acc[mt][nt] = __builtin_amdgcn_mfma_f32_16x16x32_bf16(af[mt][1], bfr[nt][1], acc[mt][nt], 0, 0, 0);
      }
  }

  const int mbase = m0 + wave_m_off + quad * 4;
  const int nbase = n0 + wn * 64 + l16;
  float bv[4];
#pragma unroll
  for (int nt = 0; nt < 4; nt++) bv[nt] = bias[nbase + nt * 16];
#pragma unroll
  for (int mt = 0; mt < MT; mt++) {
#pragma unroll
    for (int r = 0; r < 4; r++) {
      const int m = mbase + mt * 16 + r;
#pragma unroll
      for (int nt = 0; nt < 4; nt++) {
        const int n = nbase + nt * 16;
        float val = acc[mt][nt][r] + bv[nt];
        if (ACT == 1) val = gelu_fast(val);
        if (HAS_RES) val += res[(size_t)m * N + n];
        stv(&C[(size_t)m * N + n], val);
      }
    }
  }
}

// ---------------- Flash attention, transposed form (S^T / O^T) ----------------
// Per wave: 16 q-rows, 64-key chunks. Q pre-scaled by log2e/8 so p = exp2(S)
// (one v_exp_f32). Softmax denominator via ones-row MFMA (l^T = 1^T @ P^T,
// accumulated across chunks) — no VALU adds, no final cross-lane reduction.
__global__ __launch_bounds__(256) void attn_mfma(const bf16* __restrict__ qkv,
                                                 const bf16* __restrict__ vT,
                                                 bf16* __restrict__ y) {
  const int qt = blockIdx.x, h = blockIdx.y, b = blockIdx.z;
  const int tid  = threadIdx.x;
  const int wave = tid >> 6, lane = tid & 63;
  const int quad = lane >> 4, l16 = lane & 15;
  const int sw8  = l16 & 7;

  __shared__ __align__(16) bf16 Ks[64 * 64];
  __shared__ __align__(16) bf16 Vs[64 * 64];
  __shared__ __align__(16) bf16 Ps[4][16 * 64];

  const size_t base = (size_t)b * SEQ * 3072;
  const int q0 = qt * 64 + wave * 16;

  // Q fragment (B-operand), pre-scaled by log2e/8 (exp2 domain)
  const bf16* qrow = qkv + base + (size_t)(q0 + l16) * 3072 + h * HDIM;
  short8 qb0 = *(const short8*)(qrow + quad * 8);
  short8 qb1 = *(const short8*)(qrow + 32 + quad * 8);
  {
    bf16* p0 = (bf16*)&qb0; bf16* p1 = (bf16*)&qb1;
#pragma unroll
    for (int j = 0; j < 8; j++) {
      p0[j] = __float2bfloat16(__bfloat162float(p0[j]) * 0.1803368801f);
      p1[j] = __float2bfloat16(__bfloat162float(p1[j]) * 0.1803368801f);
    }
  }

  // ones A-frag for the denominator MFMA
  short8 ones;
  {
    bf16 one = __float2bfloat16(1.0f);
    bf16* o = (bf16*)&ones;
#pragma unroll
    for (int j = 0; j < 8; j++) o[j] = one;
  }

  floatx4 O[4];
#pragma unroll
  for (int c = 0; c < 4; c++) O[c] = (floatx4){0.f, 0.f, 0.f, 0.f};
  floatx4 Lacc = (floatx4){0.f, 0.f, 0.f, 0.f};

  const int skey = tid >> 3, sc = tid & 7;
  const int gcol = (sc ^ (skey & 7)) * 8;
  const bf16* kg = qkv + base + D_MODEL + h * HDIM;
  const bf16* vg = vT + (size_t)(h * HDIM) * (size_t)ROWS + b * SEQ;

  for (int kt = 0; kt < SEQ; kt += 64) {
    __syncthreads();
    load_lds16(kg + (size_t)(kt + skey) * 3072 + gcol,      &Ks[tid * 8]);
    load_lds16(kg + (size_t)(kt + skey + 32) * 3072 + gcol, &Ks[(tid + 256) * 8]);
    load_lds16(vg + (size_t)skey * ROWS + kt + gcol,        &Vs[tid * 8]);
    load_lds16(vg + (size_t)(skey + 32) * ROWS + kt + gcol, &Vs[(tid + 256) * 8]);
    __syncthreads();

    // S^T = K @ Q^T; p = exp2(S); store P^T as b64
#pragma unroll
    for (int g = 0; g < 4; g++) {
      floatx4 S = (floatx4){0.f, 0.f, 0.f, 0.f};
      const short8 ka0 = *(const short8*)&Ks[(g * 16 + l16) * 64 + ((quad    ) ^ sw8) * 8];
      const short8 ka1 = *(const short8*)&Ks[(g * 16 + l16) * 64 + ((quad + 4) ^ sw8) * 8];
      S = __builtin_amdgcn_mfma_f32_16x16x32_bf16(ka0, qb0, S, 0, 0, 0);
      S = __builtin_amdgcn_mfma_f32_16x16x32_bf16(ka1, qb1, S, 0, 0, 0);
      bf16 pb[4];
#pragma unroll
      for (int r = 0; r < 4; r++) pb[r] = __float2bfloat16(EXP2(S[r]));
      const int chunk = 2 * g + (quad >> 1);
      *(short4v*)&Ps[wave][l16 * 64 + (chunk ^ sw8) * 8 + (quad & 1) * 4] =
          *(const short4v*)pb;
    }

    const short8 pb0 = *(const short8*)&Ps[wave][l16 * 64 + ((quad    ) ^ sw8) * 8];
    const short8 pb1 = *(const short8*)&Ps[wave][l16 * 64 + ((quad + 4) ^ sw8) * 8];

    // denominator: Lacc += 1^T @ P^T (every lane ends with l(q=l16))
    Lacc = __builtin_amdgcn_mfma_f32_16x16x32_bf16(ones, pb0, Lacc, 0, 0, 0);
    Lacc = __builtin_amdgcn_mfma_f32_16x16x32_bf16(ones, pb1, Lacc, 0, 0, 0);

    // O^T += V^T @ P^T
#pragma unroll
    for (int c = 0; c < 4; c++) {
      const short8 va0 = *(const short8*)&Vs[(c * 16 + l16) * 64 + ((quad    ) ^ sw8) * 8];
      const short8 va1 = *(const short8*)&Vs[(c * 16 + l16) * 64 + ((quad + 4) ^ sw8) * 8];
      O[c] = __builtin_amdgcn_mfma_f32_16x16x32_bf16(va0, pb0, O[c], 0, 0, 0);
      O[c] = __builtin_amdgcn_mfma_f32_16x16x32_bf16(va1, pb1, O[c], 0, 0, 0);
    }
  }

  const float inv = 1.0f / Lacc[0];

  bf16* yrow = y + (size_t)(b * SEQ + q0 + l16) * D_MODEL + h * HDIM + quad * 4;
#pragma unroll
  for (int c = 0; c < 4; c++) {
    bf16 ov[4];
#pragma unroll
    for (int r = 0; r < 4; r++) ov[r] = __float2bfloat16(O[c][r] * inv);
    *(short4v*)(yrow + c * 16) = *(const short4v*)ov;
  }
}

extern "C" void kernel_launch(void* const* d_in, const int* in_sizes, int n_in,
                              void* d_out, int out_size, void* d_ws, size_t ws_size,
                              hipStream_t stream) {
  const float* x      = (const float*)d_in[0];
  const float* ln1_g  = (const float*)d_in[1];
  const float* ln1_b  = (const float*)d_in[2];
  const float* ln2_g  = (const float*)d_in[3];
  const float* ln2_b  = (const float*)d_in[4];
  const float* w_qkv  = (const float*)d_in[5];
  const float* b_qkv  = (const float*)d_in[6];
  const float* w_proj = (const float*)d_in[7];
  const float* b_proj = (const float*)d_in[8];
  const float* w_fc1  = (const float*)d_in[9];
  const float* b_fc1  = (const float*)d_in[10];
  const float* w_fc2  = (const float*)d_in[11];
  const float* b_fc2  = (const float*)d_in[12];
  float* out = (float*)d_out;

  // Workspace map (88 MiB high-water):
  //   [ 0, 8M)  h        [ 8,32M) qkv      [ 8,16M) wt_fc1 (post-attn)
  //   [16,24M)  wt_fc2 (post-attn)          [32,40M) y
  //   [40,56M)  x1 (f32) [56,88M) ffh      [56,62M) wt_qkv  [62,64M) wt_proj
  //   [64,72M)  vT (dead before ffh written)
  char* ws = (char*)d_ws;
  bf16*  h       = (bf16*)(ws);
  bf16*  qkv     = (bf16*)(ws + (8u  << 20));
  bf16*  wt_fc1  = (bf16*)(ws + (8u  << 20));
  bf16*  wt_fc2  = (bf16*)(ws + (16u << 20));
  bf16*  y       = (bf16*)(ws + (32u << 20));
  float* x1      = (float*)(ws + (40u << 20));
  bf16*  ffh     = (bf16*)(ws + (56u << 20));
  bf16*  wt_qkv  = (bf16*)(ws + (56u << 20));
  bf16*  wt_proj = (bf16*)(ws + (62u << 20));
  bf16*  vT      = (bf16*)(ws + (64u << 20));

  // qkv + proj weight converts (one dispatch)
  convert_w2<<<768 + 256, 256, 0, stream>>>(w_qkv, wt_qkv, 1024, 3072, 768,
                                            w_proj, wt_proj, 1024, 1024);
  // 1. h = LN1(x)
  ln_kernel<float><<<ROWS, 256, 0, stream>>>(x, ln1_g, ln1_b, h);
  // 2. qkv = h @ w_qkv + b_qkv   (128x128, 768 blocks, XCD-swizzled)
  gemm_mfma<0, false, 128, 128, bf16><<<768, 256, 0, stream>>>(
      h, wt_qkv, b_qkv, nullptr, qkv, ROWS, 3072, D_MODEL, 24);
  // 2b. vT = V^T
  v_transpose<<<dim3(ROWS / 64, 1024 / 64), 256, 0, stream>>>(qkv, vT);
  // 3. y = softmax(q k^T / 8) v
  attn_mfma<<<dim3(SEQ / 64, NHEAD, BATCH), 256, 0, stream>>>(qkv, vT, y);
  // fc1 + fc2 weight converts (one dispatch; must follow attn: overlays qkv)
  convert_w2<<<1024 + 1024, 256, 0, stream>>>(w_fc1, wt_fc1, 1024, 4096, 1024,
                                              w_fc2, wt_fc2, 4096, 1024);
  // 4. x1 = x + y @ w_proj + b_proj   (64x64 tiles, 1024 blocks)
  gemm_mfma<0, true, 64, 64, float><<<1024, 256, 0, stream>>>(
      y, wt_proj, b_proj, x, x1, ROWS, D_MODEL, D_MODEL, 16);
  // 5. h = LN2(x1)
  ln_kernel<float><<<ROWS, 256, 0, stream>>>(x1, ln2_g, ln2_b, h);
  // 6. ffh = gelu(h @ w_fc1 + b_fc1)   (128x128, 1024 blocks)
  gemm_mfma<1, false, 128, 128, bf16><<<1024, 256, 0, stream>>>(
      h, wt_fc1, b_fc1, nullptr, ffh, ROWS, FFDIM, D_MODEL, 32);
  // 7. out = x1 + ffh @ w_fc2 + b_fc2   (64x64 tiles, 1024 blocks)
  gemm_mfma<0, true, 64, 64, float><<<1024, 256, 0, stream>>>(
      ffh, wt_fc2, b_fc2, x1, out, ROWS, D_MODEL, FFDIM, 16);
}

// Round 12
// 352.798 us; speedup vs baseline: 1.0278x; 1.0012x over previous
//
#include <hip/hip_runtime.h>
#include <hip/hip_bf16.h>
#include <math.h>

typedef __hip_bfloat16 bf16;
typedef __attribute__((ext_vector_type(8))) short short8;
typedef __attribute__((ext_vector_type(4))) short short4v;
typedef __attribute__((ext_vector_type(4))) float floatx4;

#define D_MODEL 1024
#define SEQ     2048
#define BATCH   2
#define NHEAD   16
#define HDIM    64
#define FFDIM   4096
#define ROWS    (BATCH*SEQ)   // 4096 token rows

#if __has_builtin(__builtin_amdgcn_exp2f)
#define EXP2(x) __builtin_amdgcn_exp2f(x)
#else
#define EXP2(x) exp2f(x)
#endif

__device__ __forceinline__ void stv(bf16* p, float v)  { *p = __float2bfloat16(v); }
__device__ __forceinline__ void stv(float* p, float v) { *p = v; }

__device__ __forceinline__ void load_lds16(const bf16* g, bf16* l) {
  __builtin_amdgcn_global_load_lds((const __attribute__((address_space(1))) void*)g,
                                   (__attribute__((address_space(3))) void*)l, 16, 0, 0);
}

// fast GELU: x * sigmoid(x*(c0 + c1*x^2)) == tanh-form GELU; max |err| vs exact ~4e-4
__device__ __forceinline__ float gelu_fast(float x) {
  float z = x * (1.5957691f + 0.07135481f * x * x);
  return x * __builtin_amdgcn_rcpf(1.0f + __expf(-z));
}

// ---------------- LayerNorm: one 256-thread block per row of 1024 ----------------
template<typename IN_T>
__global__ void ln_kernel(const IN_T* __restrict__ x, const float* __restrict__ g,
                          const float* __restrict__ beta, bf16* __restrict__ out) {
  const int row = blockIdx.x;
  const int tid = threadIdx.x;
  __shared__ float red[8];
  const IN_T* xr = x + (size_t)row * D_MODEL;
  float v[4], s = 0.f, ss = 0.f;
#pragma unroll
  for (int i = 0; i < 4; i++) {
    float val = (float)xr[tid + i * 256];
    v[i] = val; s += val; ss += val * val;
  }
#pragma unroll
  for (int off = 32; off > 0; off >>= 1) {
    s  += __shfl_down(s, off);
    ss += __shfl_down(ss, off);
  }
  if ((tid & 63) == 0) { red[tid >> 6] = s; red[4 + (tid >> 6)] = ss; }
  __syncthreads();
  s  = red[0] + red[1] + red[2] + red[3];
  ss = red[4] + red[5] + red[6] + red[7];
  const float mu  = s * (1.0f / D_MODEL);
  const float var = ss * (1.0f / D_MODEL) - mu * mu;
  const float rs  = rsqrtf(var + 1e-5f);
  bf16* orow = out + (size_t)row * D_MODEL;
#pragma unroll
  for (int i = 0; i < 4; i++) {
    int c = tid + i * 256;
    stv(orow + c, (v[i] - mu) * rs * g[c] + beta[c]);
  }
}

// -------- W[K][N] f32 -> Wt[N][K] bf16, two jobs batched in one dispatch --------
__device__ __forceinline__ void convert_tile(const float* W, bf16* Wt,
                                             int K, int N, int n0, int k0, int tid) {
  __shared__ float tile[64][65];
  const int r = tid >> 2, c0 = (tid & 3) * 16;
#pragma unroll
  for (int j = 0; j < 16; j += 4) {
    float4 v = *(const float4*)&W[(size_t)(k0 + r) * N + n0 + c0 + j];
    tile[r][c0 + j]     = v.x; tile[r][c0 + j + 1] = v.y;
    tile[r][c0 + j + 2] = v.z; tile[r][c0 + j + 3] = v.w;
  }
  __syncthreads();
  bf16 ov[16];
#pragma unroll
  for (int j = 0; j < 16; j++) ov[j] = __float2bfloat16(tile[c0 + j][r]);
  *(short8*)&Wt[(size_t)(n0 + r) * K + k0 + c0]     = *(const short8*)&ov[0];
  *(short8*)&Wt[(size_t)(n0 + r) * K + k0 + c0 + 8] = *(const short8*)&ov[8];
}

__global__ __launch_bounds__(256) void convert_w2(
    const float* __restrict__ W0, bf16* __restrict__ Wt0, int K0, int N0, int tiles0,
    const float* __restrict__ W1, bf16* __restrict__ Wt1, int K1, int N1) {
  int bid = blockIdx.x;
  const int tid = threadIdx.x;
  if (bid < tiles0) {
    const int nt = N0 >> 6;
    convert_tile(W0, Wt0, K0, N0, (bid % nt) * 64, (bid / nt) * 64, tid);
  } else {
    bid -= tiles0;
    const int nt = N1 >> 6;
    convert_tile(W1, Wt1, K1, N1, (bid % nt) * 64, (bid / nt) * 64, tid);
  }
}

// ------------- V-transpose: vT[h*64+d][b*2048+t] = qkv[b*2048+t][2048+h*64+d] ----
__global__ __launch_bounds__(256) void v_transpose(const bf16* __restrict__ qkv,
                                                   bf16* __restrict__ vT) {
  __shared__ bf16 tile[64][72];
  const int m0 = blockIdx.x * 64;
  const int d0 = blockIdx.y * 64;
  const int tid = threadIdx.x;
  const int r = tid >> 2, c0 = (tid & 3) * 16;
  *(short8*)&tile[r][c0]     = *(const short8*)&qkv[(size_t)(m0 + r) * 3072 + 2048 + d0 + c0];
  *(short8*)&tile[r][c0 + 8] = *(const short8*)&qkv[(size_t)(m0 + r) * 3072 + 2048 + d0 + c0 + 8];
  __syncthreads();
  bf16 ov[16];
#pragma unroll
  for (int j = 0; j < 16; j++) ov[j] = tile[c0 + j][r];
  *(short8*)&vT[(size_t)(d0 + r) * (size_t)ROWS + m0 + c0]     = *(const short8*)&ov[0];
  *(short8*)&vT[(size_t)(d0 + r) * (size_t)ROWS + m0 + c0 + 8] = *(const short8*)&ov[8];
}

// ----- Big MFMA GEMM (m97-mimic): 128x128 tile, BK=32, 16 KB LDS ----------------
// 4 waves 2x2 of 64x64; 16 MFMA / 8 ds_read_b128 per wave-iter; 4-chunk XOR
// swizzle (chunk ^ row&3): read-side 8 dwords/bank = conflict floor.
// XCD-clustered 1D-grid swizzle as before.
template<int ACT, typename OUT_T>
__global__ __launch_bounds__(256) void gemm_mfma_bk32(
    const bf16* __restrict__ A, const bf16* __restrict__ Bt,
    const float* __restrict__ bias, OUT_T* __restrict__ C,
    int M, int N, int K, int NTI) {
  __shared__ __align__(16) bf16 As[128][32];
  __shared__ __align__(16) bf16 Bs[128][32];
  const int tid = threadIdx.x;
  const int w = tid >> 6, lane = tid & 63;
  const int quad = lane >> 4, l16 = lane & 15;
  const int wm = w >> 1, wn = w & 1;
  const int bid = blockIdx.x;
  const int n_idx = (bid >> 3) % NTI;
  const int m_idx = ((bid >> 3) / NTI) * 8 + (bid & 7);
  const int m0 = m_idx * 128, n0 = n_idx * 128;

  // staging: thread -> row tid>>2 (wave w covers rows w*16..w*16+15 per load),
  // source chunk swizzled by row&3
  const int srow = tid >> 2;
  const int schunk = ((tid & 3) ^ (srow & 3)) * 8;
  const bf16* Ag = A  + (size_t)(m0 + srow) * K + schunk;
  const bf16* Bg = Bt + (size_t)(n0 + srow) * K + schunk;

  floatx4 acc[4][4];
#pragma unroll
  for (int i = 0; i < 4; i++)
#pragma unroll
    for (int j = 0; j < 4; j++) acc[i][j] = (floatx4){0.f, 0.f, 0.f, 0.f};

  const int rsw = l16 & 3;
  for (int k0 = 0; k0 < K; k0 += 32) {
    __syncthreads();
    load_lds16(Ag + k0,                    &As[w * 16][0]);
    load_lds16(Ag + k0 + (size_t)64 * K,   &As[64 + w * 16][0]);
    load_lds16(Bg + k0,                    &Bs[w * 16][0]);
    load_lds16(Bg + k0 + (size_t)64 * K,   &Bs[64 + w * 16][0]);
    __syncthreads();
    short8 af[4], bfr[4];
#pragma unroll
    for (int t = 0; t < 4; t++) {
      af[t]  = *(const short8*)&As[wm * 64 + t * 16 + l16][(quad ^ rsw) * 8];
      bfr[t] = *(const short8*)&Bs[wn * 64 + t * 16 + l16][(quad ^ rsw) * 8];
    }
#pragma unroll
    for (int mt = 0; mt < 4; mt++)
#pragma unroll
      for (int nt = 0; nt < 4; nt++)
        acc[mt][nt] = __builtin_amdgcn_mfma_f32_16x16x32_bf16(af[mt], bfr[nt], acc[mt][nt], 0, 0, 0);
  }

  const int mbase = m0 + wm * 64 + quad * 4;
  const int nbase = n0 + wn * 64 + l16;
  float bv[4];
#pragma unroll
  for (int nt = 0; nt < 4; nt++) bv[nt] = bias[nbase + nt * 16];
#pragma unroll
  for (int mt = 0; mt < 4; mt++) {
#pragma unroll
    for (int r = 0; r < 4; r++) {
      const int m = mbase + mt * 16 + r;
#pragma unroll
      for (int nt = 0; nt < 4; nt++) {
        const int n = nbase + nt * 16;
        float val = acc[mt][nt][r] + bv[nt];
        if (ACT == 1) val = gelu_fast(val);
        stv(&C[(size_t)m * N + n], val);
      }
    }
  }
}

// ------- Narrow MFMA GEMM (proven): tile 64x64, BK=64, +bias +res ---------------
template<bool HAS_RES, typename OUT_T>
__global__ __launch_bounds__(256) void gemm_mfma(
    const bf16* __restrict__ A, const bf16* __restrict__ Bt,
    const float* __restrict__ bias, const float* __restrict__ res,
    OUT_T* __restrict__ C, int M, int N, int K, int NTI) {
  __shared__ __align__(16) bf16 As[64][64];
  __shared__ __align__(16) bf16 Bs[64][64];
  const int tid = threadIdx.x;
  const int w = tid >> 6, lane = tid & 63;
  const int quad = lane >> 4, l16 = lane & 15;
  const int bid = blockIdx.x;
  const int n_idx = (bid >> 3) % NTI;
  const int m_idx = ((bid >> 3) / NTI) * 8 + (bid & 7);
  const int m0 = m_idx * 64, n0 = n_idx * 64;
  const int csw = (lane & 7) ^ (lane >> 3);

  const bf16* Ag = A  + (size_t)(m0 + (tid >> 3)) * K + csw * 8;
  const bf16* Bg = Bt + (size_t)(n0 + (tid >> 3)) * K + csw * 8;

  floatx4 acc[1][4];
#pragma unroll
  for (int j = 0; j < 4; j++) acc[0][j] = (floatx4){0.f, 0.f, 0.f, 0.f};

  const int sw = l16 & 7;
  for (int k0 = 0; k0 < K; k0 += 64) {
    __syncthreads();
#pragma unroll
    for (int j = 0; j < 2; j++) {
      load_lds16(Ag + k0 + (size_t)j * 32 * K, &As[j * 32 + (tid >> 3)][0]);
      load_lds16(Bg + k0 + (size_t)j * 32 * K, &Bs[j * 32 + (tid >> 3)][0]);
    }
    __syncthreads();
    short8 af[2], bfr[4][2];
#pragma unroll
    for (int hh = 0; hh < 2; hh++) {
      int cc = ((quad + hh * 4) ^ sw) * 8;
      af[hh] = *(const short8*)&As[w * 16 + l16][cc];
    }
#pragma unroll
    for (int t = 0; t < 4; t++)
#pragma unroll
      for (int hh = 0; hh < 2; hh++) {
        int cc = ((quad + hh * 4) ^ sw) * 8;
        bfr[t][hh] = *(const short8*)&Bs[t * 16 + l16][cc];
      }
#pragma unroll
    for (int nt = 0; nt < 4; nt++) {
      acc[0][nt] = __builtin_amdgcn_mfma_f32_16x16x32_bf16(af[0], bfr[nt][0], acc[0][nt], 0, 0, 0);
      acc[0][nt] = __builtin_amdgcn_mfma_f32_16x16x32_bf16(af[1], bfr[nt][1], acc[0][nt], 0, 0, 0);
    }
  }

  const int mbase = m0 + w * 16 + quad * 4;
  const int nbase = n0 + l16;
  float bv[4];
#pragma unroll
  for (int nt = 0; nt < 4; nt++) bv[nt] = bias[nbase + nt * 16];
#pragma unroll
  for (int r = 0; r < 4; r++) {
    const int m = mbase + r;
#pragma unroll
    for (int nt = 0; nt < 4; nt++) {
      const int n = nbase + nt * 16;
      float val = acc[0][nt][r] + bv[nt];
      if (HAS_RES) val += res[(size_t)m * N + n];
      stv(&C[(size_t)m * N + n], val);
    }
  }
}

// ---------------- Flash attention, transposed form (S^T / O^T) ----------------
__global__ __launch_bounds__(256) void attn_mfma(const bf16* __restrict__ qkv,
                                                 const bf16* __restrict__ vT,
                                                 bf16* __restrict__ y) {
  const int qt = blockIdx.x, h = blockIdx.y, b = blockIdx.z;
  const int tid  = threadIdx.x;
  const int wave = tid >> 6, lane = tid & 63;
  const int quad = lane >> 4, l16 = lane & 15;
  const int sw8  = l16 & 7;

  __shared__ __align__(16) bf16 Ks[64 * 64];
  __shared__ __align__(16) bf16 Vs[64 * 64];
  __shared__ __align__(16) bf16 Ps[4][16 * 64];

  const size_t base = (size_t)b * SEQ * 3072;
  const int q0 = qt * 64 + wave * 16;

  const bf16* qrow = qkv + base + (size_t)(q0 + l16) * 3072 + h * HDIM;
  short8 qb0 = *(const short8*)(qrow + quad * 8);
  short8 qb1 = *(const short8*)(qrow + 32 + quad * 8);
  {
    bf16* p0 = (bf16*)&qb0; bf16* p1 = (bf16*)&qb1;
#pragma unroll
    for (int j = 0; j < 8; j++) {
      p0[j] = __float2bfloat16(__bfloat162float(p0[j]) * 0.1803368801f);
      p1[j] = __float2bfloat16(__bfloat162float(p1[j]) * 0.1803368801f);
    }
  }

  short8 ones;
  {
    bf16 one = __float2bfloat16(1.0f);
    bf16* o = (bf16*)&ones;
#pragma unroll
    for (int j = 0; j < 8; j++) o[j] = one;
  }

  floatx4 O[4];
#pragma unroll
  for (int c = 0; c < 4; c++) O[c] = (floatx4){0.f, 0.f, 0.f, 0.f};
  floatx4 Lacc = (floatx4){0.f, 0.f, 0.f, 0.f};

  const int skey = tid >> 3, sc = tid & 7;
  const int gcol = (sc ^ (skey & 7)) * 8;
  const bf16* kg = qkv + base + D_MODEL + h * HDIM;
  const bf16* vg = vT + (size_t)(h * HDIM) * (size_t)ROWS + b * SEQ;

  for (int kt = 0; kt < SEQ; kt += 64) {
    __syncthreads();
    load_lds16(kg + (size_t)(kt + skey) * 3072 + gcol,      &Ks[tid * 8]);
    load_lds16(kg + (size_t)(kt + skey + 32) * 3072 + gcol, &Ks[(tid + 256) * 8]);
    load_lds16(vg + (size_t)skey * ROWS + kt + gcol,        &Vs[tid * 8]);
    load_lds16(vg + (size_t)(skey + 32) * ROWS + kt + gcol, &Vs[(tid + 256) * 8]);
    __syncthreads();

#pragma unroll
    for (int g = 0; g < 4; g++) {
      floatx4 S = (floatx4){0.f, 0.f, 0.f, 0.f};
      const short8 ka0 = *(const short8*)&Ks[(g * 16 + l16) * 64 + ((quad    ) ^ sw8) * 8];
      const short8 ka1 = *(const short8*)&Ks[(g * 16 + l16) * 64 + ((quad + 4) ^ sw8) * 8];
      S = __builtin_amdgcn_mfma_f32_16x16x32_bf16(ka0, qb0, S, 0, 0, 0);
      S = __builtin_amdgcn_mfma_f32_16x16x32_bf16(ka1, qb1, S, 0, 0, 0);
      bf16 pb[4];
#pragma unroll
      for (int r = 0; r < 4; r++) pb[r] = __float2bfloat16(EXP2(S[r]));
      const int chunk = 2 * g + (quad >> 1);
      *(short4v*)&Ps[wave][l16 * 64 + (chunk ^ sw8) * 8 + (quad & 1) * 4] =
          *(const short4v*)pb;
    }

    const short8 pb0 = *(const short8*)&Ps[wave][l16 * 64 + ((quad    ) ^ sw8) * 8];
    const short8 pb1 = *(const short8*)&Ps[wave][l16 * 64 + ((quad + 4) ^ sw8) * 8];

    Lacc = __builtin_amdgcn_mfma_f32_16x16x32_bf16(ones, pb0, Lacc, 0, 0, 0);
    Lacc = __builtin_amdgcn_mfma_f32_16x16x32_bf16(ones, pb1, Lacc, 0, 0, 0);

#pragma unroll
    for (int c = 0; c < 4; c++) {
      const short8 va0 = *(const short8*)&Vs[(c * 16 + l16) * 64 + ((quad    ) ^ sw8) * 8];
      const short8 va1 = *(const short8*)&Vs[(c * 16 + l16) * 64 + ((quad + 4) ^ sw8) * 8];
      O[c] = __builtin_amdgcn_mfma_f32_16x16x32_bf16(va0, pb0, O[c], 0, 0, 0);
      O[c] = __builtin_amdgcn_mfma_f32_16x16x32_bf16(va1, pb1, O[c], 0, 0, 0);
    }
  }

  const float inv = 1.0f / Lacc[0];

  bf16* yrow = y + (size_t)(b * SEQ + q0 + l16) * D_MODEL + h * HDIM + quad * 4;
#pragma unroll
  for (int c = 0; c < 4; c++) {
    bf16 ov[4];
#pragma unroll
    for (int r = 0; r < 4; r++) ov[r] = __float2bfloat16(O[c][r] * inv);
    *(short4v*)(yrow + c * 16) = *(const short4v*)ov;
  }
}

extern "C" void kernel_launch(void* const* d_in, const int* in_sizes, int n_in,
                              void* d_out, int out_size, void* d_ws, size_t ws_size,
                              hipStream_t stream) {
  const float* x      = (const float*)d_in[0];
  const float* ln1_g  = (const float*)d_in[1];
  const float* ln1_b  = (const float*)d_in[2];
  const float* ln2_g  = (const float*)d_in[3];
  const float* ln2_b  = (const float*)d_in[4];
  const float* w_qkv  = (const float*)d_in[5];
  const float* b_qkv  = (const float*)d_in[6];
  const float* w_proj = (const float*)d_in[7];
  const float* b_proj = (const float*)d_in[8];
  const float* w_fc1  = (const float*)d_in[9];
  const float* b_fc1  = (const float*)d_in[10];
  const float* w_fc2  = (const float*)d_in[11];
  const float* b_fc2  = (const float*)d_in[12];
  float* out = (float*)d_out;

  // Workspace map (88 MiB high-water):
  //   [ 0, 8M)  h        [ 8,32M) qkv      [ 8,16M) wt_fc1 (post-attn)
  //   [16,24M)  wt_fc2 (post-attn)          [32,40M) y
  //   [40,56M)  x1 (f32) [56,88M) ffh      [56,62M) wt_qkv  [62,64M) wt_proj
  //   [64,72M)  vT (dead before ffh written)
  char* ws = (char*)d_ws;
  bf16*  h       = (bf16*)(ws);
  bf16*  qkv     = (bf16*)(ws + (8u  << 20));
  bf16*  wt_fc1  = (bf16*)(ws + (8u  << 20));
  bf16*  wt_fc2  = (bf16*)(ws + (16u << 20));
  bf16*  y       = (bf16*)(ws + (32u << 20));
  float* x1      = (float*)(ws + (40u << 20));
  bf16*  ffh     = (bf16*)(ws + (56u << 20));
  bf16*  wt_qkv  = (bf16*)(ws + (56u << 20));
  bf16*  wt_proj = (bf16*)(ws + (62u << 20));
  bf16*  vT      = (bf16*)(ws + (64u << 20));

  // qkv + proj weight converts (one dispatch)
  convert_w2<<<768 + 256, 256, 0, stream>>>(w_qkv, wt_qkv, 1024, 3072, 768,
                                            w_proj, wt_proj, 1024, 1024);
  // 1. h = LN1(x)
  ln_kernel<float><<<ROWS, 256, 0, stream>>>(x, ln1_g, ln1_b, h);
  // 2. qkv = h @ w_qkv + b_qkv   (128x128 BK=32, 768 blocks, XCD-swizzled)
  gemm_mfma_bk32<0, bf16><<<768, 256, 0, stream>>>(
      h, wt_qkv, b_qkv, qkv, ROWS, 3072, D_MODEL, 24);
  // 2b. vT = V^T
  v_transpose<<<dim3(ROWS / 64, 1024 / 64), 256, 0, stream>>>(qkv, vT);
  // 3. y = softmax(q k^T / 8) v
  attn_mfma<<<dim3(SEQ / 64, NHEAD, BATCH), 256, 0, stream>>>(qkv, vT, y);
  // fc1 + fc2 weight converts (one dispatch; must follow attn: overlays qkv)
  convert_w2<<<1024 + 1024, 256, 0, stream>>>(w_fc1, wt_fc1, 1024, 4096, 1024,
                                              w_fc2, wt_fc2, 4096, 1024);
  // 4. x1 = x + y @ w_proj + b_proj   (64x64 tiles, 1024 blocks)
  gemm_mfma<true, float><<<1024, 256, 0, stream>>>(
      y, wt_proj, b_proj, x, x1, ROWS, D_MODEL, D_MODEL, 16);
  // 5. h = LN2(x1)
  ln_kernel<float><<<ROWS, 256, 0, stream>>>(x1, ln2_g, ln2_b, h);
  // 6. ffh = gelu(h @ w_fc1 + b_fc1)   (128x128 BK=32, 1024 blocks)
  gemm_mfma_bk32<1, bf16><<<1024, 256, 0, stream>>>(
      h, wt_fc1, b_fc1, ffh, ROWS, FFDIM, D_MODEL, 32);
  // 7. out = x1 + ffh @ w_fc2 + b_fc2   (64x64 tiles, 1024 blocks)
  gemm_mfma<true, float><<<1024, 256, 0, stream>>>(
      ffh, wt_fc2, b_fc2, x1, out, ROWS, D_MODEL, FFDIM, 16);
}

// Round 13
// 347.136 us; speedup vs baseline: 1.0445x; 1.0163x over previous
//
#include <hip/hip_runtime.h>
#include <hip/hip_bf16.h>
#include <math.h>

typedef __hip_bfloat16 bf16;
typedef __attribute__((ext_vector_type(8))) short short8;
typedef __attribute__((ext_vector_type(4))) short short4v;
typedef __attribute__((ext_vector_type(4))) float floatx4;

#define D_MODEL 1024
#define SEQ     2048
#define BATCH   2
#define NHEAD   16
#define HDIM    64
#define FFDIM   4096
#define ROWS    (BATCH*SEQ)   // 4096 token rows

#if __has_builtin(__builtin_amdgcn_exp2f)
#define EXP2(x) __builtin_amdgcn_exp2f(x)
#else
#define EXP2(x) exp2f(x)
#endif

__device__ __forceinline__ void stv(bf16* p, float v)  { *p = __float2bfloat16(v); }
__device__ __forceinline__ void stv(float* p, float v) { *p = v; }

__device__ __forceinline__ void load_lds16(const bf16* g, bf16* l) {
  __builtin_amdgcn_global_load_lds((const __attribute__((address_space(1))) void*)g,
                                   (__attribute__((address_space(3))) void*)l, 16, 0, 0);
}

// fast GELU: x * sigmoid(x*(c0 + c1*x^2)) == tanh-form GELU; max |err| vs exact ~4e-4
__device__ __forceinline__ float gelu_fast(float x) {
  float z = x * (1.5957691f + 0.07135481f * x * x);
  return x * __builtin_amdgcn_rcpf(1.0f + __expf(-z));
}

// ---------------- LayerNorm row body (shared-memory pointer passed in) ----------
template<typename IN_T>
__device__ __forceinline__ void ln_row(const IN_T* __restrict__ x,
                                       const float* __restrict__ g,
                                       const float* __restrict__ beta,
                                       bf16* __restrict__ out, int row, int tid,
                                       float* red) {
  const IN_T* xr = x + (size_t)row * D_MODEL;
  float v[4], s = 0.f, ss = 0.f;
#pragma unroll
  for (int i = 0; i < 4; i++) {
    float val = (float)xr[tid + i * 256];
    v[i] = val; s += val; ss += val * val;
  }
#pragma unroll
  for (int off = 32; off > 0; off >>= 1) {
    s  += __shfl_down(s, off);
    ss += __shfl_down(ss, off);
  }
  if ((tid & 63) == 0) { red[tid >> 6] = s; red[4 + (tid >> 6)] = ss; }
  __syncthreads();
  s  = red[0] + red[1] + red[2] + red[3];
  ss = red[4] + red[5] + red[6] + red[7];
  const float mu  = s * (1.0f / D_MODEL);
  const float var = ss * (1.0f / D_MODEL) - mu * mu;
  const float rs  = rsqrtf(var + 1e-5f);
  bf16* orow = out + (size_t)row * D_MODEL;
#pragma unroll
  for (int i = 0; i < 4; i++) {
    int c = tid + i * 256;
    stv(orow + c, (v[i] - mu) * rs * g[c] + beta[c]);
  }
}

template<typename IN_T>
__global__ void ln_kernel(const IN_T* __restrict__ x, const float* __restrict__ g,
                          const float* __restrict__ beta, bf16* __restrict__ out) {
  __shared__ float red[8];
  ln_row(x, g, beta, out, blockIdx.x, threadIdx.x, red);
}

// -------- W[K][N] f32 -> Wt[N][K] bf16 tile body (smem passed in) --------------
__device__ __forceinline__ void convert_tile(float (*tile)[65],
                                             const float* W, bf16* Wt,
                                             int K, int N, int n0, int k0, int tid) {
  const int r = tid >> 2, c0 = (tid & 3) * 16;
#pragma unroll
  for (int j = 0; j < 16; j += 4) {
    float4 v = *(const float4*)&W[(size_t)(k0 + r) * N + n0 + c0 + j];
    tile[r][c0 + j]     = v.x; tile[r][c0 + j + 1] = v.y;
    tile[r][c0 + j + 2] = v.z; tile[r][c0 + j + 3] = v.w;
  }
  __syncthreads();
  bf16 ov[16];
#pragma unroll
  for (int j = 0; j < 16; j++) ov[j] = __float2bfloat16(tile[c0 + j][r]);
  *(short8*)&Wt[(size_t)(n0 + r) * K + k0 + c0]     = *(const short8*)&ov[0];
  *(short8*)&Wt[(size_t)(n0 + r) * K + k0 + c0 + 8] = *(const short8*)&ov[8];
}

// ---- fused: LN1 (blocks 1024..5119) + qkv/proj weight converts (0..1023) ------
__global__ __launch_bounds__(256) void fused_pre(
    const float* __restrict__ x, const float* __restrict__ g,
    const float* __restrict__ beta, bf16* __restrict__ h,
    const float* __restrict__ w_qkv, bf16* __restrict__ wt_qkv,
    const float* __restrict__ w_proj, bf16* __restrict__ wt_proj) {
  __shared__ __align__(16) float tile[64][65];
  int bid = blockIdx.x;
  const int tid = threadIdx.x;
  if (bid < 768) {
    convert_tile(tile, w_qkv, wt_qkv, 1024, 3072, (bid % 48) * 64, (bid / 48) * 64, tid);
  } else if (bid < 1024) {
    bid -= 768;
    convert_tile(tile, w_proj, wt_proj, 1024, 1024, (bid % 16) * 64, (bid / 16) * 64, tid);
  } else {
    ln_row(x, g, beta, h, bid - 1024, tid, &tile[0][0]);
  }
}

// ------------- V-transpose: vT[h*64+d][b*2048+t] = qkv[b*2048+t][2048+h*64+d] ----
__global__ __launch_bounds__(256) void v_transpose(const bf16* __restrict__ qkv,
                                                   bf16* __restrict__ vT) {
  __shared__ bf16 tile[64][72];
  const int m0 = blockIdx.x * 64;
  const int d0 = blockIdx.y * 64;
  const int tid = threadIdx.x;
  const int r = tid >> 2, c0 = (tid & 3) * 16;
  *(short8*)&tile[r][c0]     = *(const short8*)&qkv[(size_t)(m0 + r) * 3072 + 2048 + d0 + c0];
  *(short8*)&tile[r][c0 + 8] = *(const short8*)&qkv[(size_t)(m0 + r) * 3072 + 2048 + d0 + c0 + 8];
  __syncthreads();
  bf16 ov[16];
#pragma unroll
  for (int j = 0; j < 16; j++) ov[j] = tile[c0 + j][r];
  *(short8*)&vT[(size_t)(d0 + r) * (size_t)ROWS + m0 + c0]     = *(const short8*)&ov[0];
  *(short8*)&vT[(size_t)(d0 + r) * (size_t)ROWS + m0 + c0 + 8] = *(const short8*)&ov[8];
}

// ----- Big MFMA GEMM (m97-mimic): 128x128 tile, BK=32, 16 KB LDS ----------------
// Swizzle key (row>>1)&3: per 8 consecutive lanes the b128 reads cover all 4
// chunk slots in both bank halves = 32 distinct banks -> conflict-free.
template<int ACT, typename OUT_T>
__global__ __launch_bounds__(256) void gemm_mfma_bk32(
    const bf16* __restrict__ A, const bf16* __restrict__ Bt,
    const float* __restrict__ bias, OUT_T* __restrict__ C,
    int M, int N, int K, int NTI) {
  __shared__ __align__(16) bf16 As[128][32];
  __shared__ __align__(16) bf16 Bs[128][32];
  const int tid = threadIdx.x;
  const int w = tid >> 6, lane = tid & 63;
  const int quad = lane >> 4, l16 = lane & 15;
  const int wm = w >> 1, wn = w & 1;
  const int bid = blockIdx.x;
  const int n_idx = (bid >> 3) % NTI;
  const int m_idx = ((bid >> 3) / NTI) * 8 + (bid & 7);
  const int m0 = m_idx * 128, n0 = n_idx * 128;

  const int srow = tid >> 2;
  const int schunk = ((tid & 3) ^ ((srow >> 1) & 3)) * 8;
  const bf16* Ag = A  + (size_t)(m0 + srow) * K + schunk;
  const bf16* Bg = Bt + (size_t)(n0 + srow) * K + schunk;

  floatx4 acc[4][4];
#pragma unroll
  for (int i = 0; i < 4; i++)
#pragma unroll
    for (int j = 0; j < 4; j++) acc[i][j] = (floatx4){0.f, 0.f, 0.f, 0.f};

  const int rsw = (l16 >> 1) & 3;
  for (int k0 = 0; k0 < K; k0 += 32) {
    __syncthreads();
    load_lds16(Ag + k0,                    &As[w * 16][0]);
    load_lds16(Ag + k0 + (size_t)64 * K,   &As[64 + w * 16][0]);
    load_lds16(Bg + k0,                    &Bs[w * 16][0]);
    load_lds16(Bg + k0 + (size_t)64 * K,   &Bs[64 + w * 16][0]);
    __syncthreads();
    short8 af[4], bfr[4];
#pragma unroll
    for (int t = 0; t < 4; t++) {
      af[t]  = *(const short8*)&As[wm * 64 + t * 16 + l16][(quad ^ rsw) * 8];
      bfr[t] = *(const short8*)&Bs[wn * 64 + t * 16 + l16][(quad ^ rsw) * 8];
    }
#pragma unroll
    for (int mt = 0; mt < 4; mt++)
#pragma unroll
      for (int nt = 0; nt < 4; nt++)
        acc[mt][nt] = __builtin_amdgcn_mfma_f32_16x16x32_bf16(af[mt], bfr[nt], acc[mt][nt], 0, 0, 0);
  }

  const int mbase = m0 + wm * 64 + quad * 4;
  const int nbase = n0 + wn * 64 + l16;
  float bv[4];
#pragma unroll
  for (int nt = 0; nt < 4; nt++) bv[nt] = bias[nbase + nt * 16];
#pragma unroll
  for (int mt = 0; mt < 4; mt++) {
#pragma unroll
    for (int r = 0; r < 4; r++) {
      const int m = mbase + mt * 16 + r;
#pragma unroll
      for (int nt = 0; nt < 4; nt++) {
        const int n = nbase + nt * 16;
        float val = acc[mt][nt][r] + bv[nt];
        if (ACT == 1) val = gelu_fast(val);
        stv(&C[(size_t)m * N + n], val);
      }
    }
  }
}

// ------- Narrow MFMA GEMM body: tile 64x64, BK=64, +bias (+res) -----------------
template<bool HAS_RES, typename OUT_T>
__device__ __forceinline__ void gemm64_body(
    bf16 (*As)[64], bf16 (*Bs)[64],
    const bf16* __restrict__ A, const bf16* __restrict__ Bt,
    const float* __restrict__ bias, const float* __restrict__ res,
    OUT_T* __restrict__ C, int M, int N, int K, int NTI, int bid, int tid) {
  const int w = tid >> 6, lane = tid & 63;
  const int quad = lane >> 4, l16 = lane & 15;
  const int n_idx = (bid >> 3) % NTI;
  const int m_idx = ((bid >> 3) / NTI) * 8 + (bid & 7);
  const int m0 = m_idx * 64, n0 = n_idx * 64;
  const int csw = (lane & 7) ^ (lane >> 3);

  const bf16* Ag = A  + (size_t)(m0 + (tid >> 3)) * K + csw * 8;
  const bf16* Bg = Bt + (size_t)(n0 + (tid >> 3)) * K + csw * 8;

  floatx4 acc[4];
#pragma unroll
  for (int j = 0; j < 4; j++) acc[j] = (floatx4){0.f, 0.f, 0.f, 0.f};

  const int sw = l16 & 7;
  for (int k0 = 0; k0 < K; k0 += 64) {
    __syncthreads();
#pragma unroll
    for (int j = 0; j < 2; j++) {
      load_lds16(Ag + k0 + (size_t)j * 32 * K, &As[j * 32 + (tid >> 3)][0]);
      load_lds16(Bg + k0 + (size_t)j * 32 * K, &Bs[j * 32 + (tid >> 3)][0]);
    }
    __syncthreads();
    short8 af[2], bfr[4][2];
#pragma unroll
    for (int hh = 0; hh < 2; hh++) {
      int cc = ((quad + hh * 4) ^ sw) * 8;
      af[hh] = *(const short8*)&As[w * 16 + l16][cc];
    }
#pragma unroll
    for (int t = 0; t < 4; t++)
#pragma unroll
      for (int hh = 0; hh < 2; hh++) {
        int cc = ((quad + hh * 4) ^ sw) * 8;
        bfr[t][hh] = *(const short8*)&Bs[t * 16 + l16][cc];
      }
#pragma unroll
    for (int nt = 0; nt < 4; nt++) {
      acc[nt] = __builtin_amdgcn_mfma_f32_16x16x32_bf16(af[0], bfr[nt][0], acc[nt], 0, 0, 0);
      acc[nt] = __builtin_amdgcn_mfma_f32_16x16x32_bf16(af[1], bfr[nt][1], acc[nt], 0, 0, 0);
    }
  }

  const int mbase = m0 + w * 16 + quad * 4;
  const int nbase = n0 + l16;
  float bv[4];
#pragma unroll
  for (int nt = 0; nt < 4; nt++) bv[nt] = bias[nbase + nt * 16];
#pragma unroll
  for (int r = 0; r < 4; r++) {
    const int m = mbase + r;
#pragma unroll
    for (int nt = 0; nt < 4; nt++) {
      const int n = nbase + nt * 16;
      float val = acc[nt][r] + bv[nt];
      if (HAS_RES) val += res[(size_t)m * N + n];
      stv(&C[(size_t)m * N + n], val);
    }
  }
}

template<bool HAS_RES, typename OUT_T>
__global__ __launch_bounds__(256) void gemm_mfma64(
    const bf16* __restrict__ A, const bf16* __restrict__ Bt,
    const float* __restrict__ bias, const float* __restrict__ res,
    OUT_T* __restrict__ C, int M, int N, int K, int NTI) {
  __shared__ __align__(16) bf16 As[64][64];
  __shared__ __align__(16) bf16 Bs[64][64];
  gemm64_body<HAS_RES>(As, Bs, A, Bt, bias, res, C, M, N, K, NTI,
                       blockIdx.x, threadIdx.x);
}

// ---- fused: proj GEMM (blocks 0..1023) + fc1/fc2 weight converts (1024..3071) --
__global__ __launch_bounds__(256) void fused_mid(
    const bf16* __restrict__ y, const bf16* __restrict__ wt_proj,
    const float* __restrict__ b_proj, const float* __restrict__ x,
    float* __restrict__ x1,
    const float* __restrict__ w_fc1, bf16* __restrict__ wt_fc1,
    const float* __restrict__ w_fc2, bf16* __restrict__ wt_fc2) {
  __shared__ __align__(16) char smem[16640];
  int bid = blockIdx.x;
  const int tid = threadIdx.x;
  if (bid >= 1024) {
    bid -= 1024;
    float (*tile)[65] = (float(*)[65])smem;
    if (bid < 1024)
      convert_tile(tile, w_fc1, wt_fc1, 1024, 4096, (bid % 64) * 64, (bid / 64) * 64, tid);
    else {
      bid -= 1024;
      convert_tile(tile, w_fc2, wt_fc2, 4096, 1024, (bid % 16) * 64, (bid / 16) * 64, tid);
    }
    return;
  }
  bf16 (*As)[64] = (bf16(*)[64])smem;
  bf16 (*Bs)[64] = (bf16(*)[64])(smem + 8192);
  gemm64_body<true>(As, Bs, y, wt_proj, b_proj, x, x1,
                    ROWS, D_MODEL, D_MODEL, 16, bid, tid);
}

// ---------------- Flash attention, transposed form (S^T / O^T) ----------------
__global__ __launch_bounds__(256) void attn_mfma(const bf16* __restrict__ qkv,
                                                 const bf16* __restrict__ vT,
                                                 bf16* __restrict__ y) {
  const int qt = blockIdx.x, h = blockIdx.y, b = blockIdx.z;
  const int tid  = threadIdx.x;
  const int wave = tid >> 6, lane = tid & 63;
  const int quad = lane >> 4, l16 = lane & 15;
  const int sw8  = l16 & 7;

  __shared__ __align__(16) bf16 Ks[64 * 64];
  __shared__ __align__(16) bf16 Vs[64 * 64];
  __shared__ __align__(16) bf16 Ps[4][16 * 64];

  const size_t base = (size_t)b * SEQ * 3072;
  const int q0 = qt * 64 + wave * 16;

  const bf16* qrow = qkv + base + (size_t)(q0 + l16) * 3072 + h * HDIM;
  short8 qb0 = *(const short8*)(qrow + quad * 8);
  short8 qb1 = *(const short8*)(qrow + 32 + quad * 8);
  {
    bf16* p0 = (bf16*)&qb0; bf16* p1 = (bf16*)&qb1;
#pragma unroll
    for (int j = 0; j < 8; j++) {
      p0[j] = __float2bfloat16(__bfloat162float(p0[j]) * 0.1803368801f);
      p1[j] = __float2bfloat16(__bfloat162float(p1[j]) * 0.1803368801f);
    }
  }

  short8 ones;
  {
    bf16 one = __float2bfloat16(1.0f);
    bf16* o = (bf16*)&ones;
#pragma unroll
    for (int j = 0; j < 8; j++) o[j] = one;
  }

  floatx4 O[4];
#pragma unroll
  for (int c = 0; c < 4; c++) O[c] = (floatx4){0.f, 0.f, 0.f, 0.f};
  floatx4 Lacc = (floatx4){0.f, 0.f, 0.f, 0.f};

  const int skey = tid >> 3, sc = tid & 7;
  const int gcol = (sc ^ (skey & 7)) * 8;
  const bf16* kg = qkv + base + D_MODEL + h * HDIM;
  const bf16* vg = vT + (size_t)(h * HDIM) * (size_t)ROWS + b * SEQ;

  for (int kt = 0; kt < SEQ; kt += 64) {
    __syncthreads();
    load_lds16(kg + (size_t)(kt + skey) * 3072 + gcol,      &Ks[tid * 8]);
    load_lds16(kg + (size_t)(kt + skey + 32) * 3072 + gcol, &Ks[(tid + 256) * 8]);
    load_lds16(vg + (size_t)skey * ROWS + kt + gcol,        &Vs[tid * 8]);
    load_lds16(vg + (size_t)(skey + 32) * ROWS + kt + gcol, &Vs[(tid + 256) * 8]);
    __syncthreads();

#pragma unroll
    for (int g = 0; g < 4; g++) {
      floatx4 S = (floatx4){0.f, 0.f, 0.f, 0.f};
      const short8 ka0 = *(const short8*)&Ks[(g * 16 + l16) * 64 + ((quad    ) ^ sw8) * 8];
      const short8 ka1 = *(const short8*)&Ks[(g * 16 + l16) * 64 + ((quad + 4) ^ sw8) * 8];
      S = __builtin_amdgcn_mfma_f32_16x16x32_bf16(ka0, qb0, S, 0, 0, 0);
      S = __builtin_amdgcn_mfma_f32_16x16x32_bf16(ka1, qb1, S, 0, 0, 0);
      bf16 pb[4];
#pragma unroll
      for (int r = 0; r < 4; r++) pb[r] = __float2bfloat16(EXP2(S[r]));
      const int chunk = 2 * g + (quad >> 1);
      *(short4v*)&Ps[wave][l16 * 64 + (chunk ^ sw8) * 8 + (quad & 1) * 4] =
          *(const short4v*)pb;
    }

    const short8 pb0 = *(const short8*)&Ps[wave][l16 * 64 + ((quad    ) ^ sw8) * 8];
    const short8 pb1 = *(const short8*)&Ps[wave][l16 * 64 + ((quad + 4) ^ sw8) * 8];

    Lacc = __builtin_amdgcn_mfma_f32_16x16x32_bf16(ones, pb0, Lacc, 0, 0, 0);
    Lacc = __builtin_amdgcn_mfma_f32_16x16x32_bf16(ones, pb1, Lacc, 0, 0, 0);

#pragma unroll
    for (int c = 0; c < 4; c++) {
      const short8 va0 = *(const short8*)&Vs[(c * 16 + l16) * 64 + ((quad    ) ^ sw8) * 8];
      const short8 va1 = *(const short8*)&Vs[(c * 16 + l16) * 64 + ((quad + 4) ^ sw8) * 8];
      O[c] = __builtin_amdgcn_mfma_f32_16x16x32_bf16(va0, pb0, O[c], 0, 0, 0);
      O[c] = __builtin_amdgcn_mfma_f32_16x16x32_bf16(va1, pb1, O[c], 0, 0, 0);
    }
  }

  const float inv = 1.0f / Lacc[0];

  bf16* yrow = y + (size_t)(b * SEQ + q0 + l16) * D_MODEL + h * HDIM + quad * 4;
#pragma unroll
  for (int c = 0; c < 4; c++) {
    bf16 ov[4];
#pragma unroll
    for (int r = 0; r < 4; r++) ov[r] = __float2bfloat16(O[c][r] * inv);
    *(short4v*)(yrow + c * 16) = *(const short4v*)ov;
  }
}

extern "C" void kernel_launch(void* const* d_in, const int* in_sizes, int n_in,
                              void* d_out, int out_size, void* d_ws, size_t ws_size,
                              hipStream_t stream) {
  const float* x      = (const float*)d_in[0];
  const float* ln1_g  = (const float*)d_in[1];
  const float* ln1_b  = (const float*)d_in[2];
  const float* ln2_g  = (const float*)d_in[3];
  const float* ln2_b  = (const float*)d_in[4];
  const float* w_qkv  = (const float*)d_in[5];
  const float* b_qkv  = (const float*)d_in[6];
  const float* w_proj = (const float*)d_in[7];
  const float* b_proj = (const float*)d_in[8];
  const float* w_fc1  = (const float*)d_in[9];
  const float* b_fc1  = (const float*)d_in[10];
  const float* w_fc2  = (const float*)d_in[11];
  const float* b_fc2  = (const float*)d_in[12];
  float* out = (float*)d_out;

  // Workspace map (88 MiB high-water):
  //   [ 0, 8M)  h        [ 8,32M) qkv      [ 8,16M) wt_fc1 (post-attn)
  //   [16,24M)  wt_fc2 (post-attn)          [32,40M) y
  //   [40,56M)  x1 (f32) [56,88M) ffh      [56,62M) wt_qkv  [62,64M) wt_proj
  //   [64,72M)  vT (dead before ffh written)
  char* ws = (char*)d_ws;
  bf16*  h       = (bf16*)(ws);
  bf16*  qkv     = (bf16*)(ws + (8u  << 20));
  bf16*  wt_fc1  = (bf16*)(ws + (8u  << 20));
  bf16*  wt_fc2  = (bf16*)(ws + (16u << 20));
  bf16*  y       = (bf16*)(ws + (32u << 20));
  float* x1      = (float*)(ws + (40u << 20));
  bf16*  ffh     = (bf16*)(ws + (56u << 20));
  bf16*  wt_qkv  = (bf16*)(ws + (56u << 20));
  bf16*  wt_proj = (bf16*)(ws + (62u << 20));
  bf16*  vT      = (bf16*)(ws + (64u << 20));

  // 1. LN1 + qkv/proj weight converts (one dispatch)
  fused_pre<<<1024 + ROWS, 256, 0, stream>>>(x, ln1_g, ln1_b, h,
                                             w_qkv, wt_qkv, w_proj, wt_proj);
  // 2. qkv = h @ w_qkv + b_qkv   (128x128 BK=32, 768 blocks, XCD-swizzled)
  gemm_mfma_bk32<0, bf16><<<768, 256, 0, stream>>>(
      h, wt_qkv, b_qkv, qkv, ROWS, 3072, D_MODEL, 24);
  // 2b. vT = V^T
  v_transpose<<<dim3(ROWS / 64, 1024 / 64), 256, 0, stream>>>(qkv, vT);
  // 3. y = softmax(q k^T / 8) v
  attn_mfma<<<dim3(SEQ / 64, NHEAD, BATCH), 256, 0, stream>>>(qkv, vT, y);
  // 4. proj (+x residual) fused with fc1/fc2 weight converts (qkv dead now)
  fused_mid<<<3072, 256, 0, stream>>>(y, wt_proj, b_proj, x, x1,
                                      w_fc1, wt_fc1, w_fc2, wt_fc2);
  // 5. h = LN2(x1)
  ln_kernel<float><<<ROWS, 256, 0, stream>>>(x1, ln2_g, ln2_b, h);
  // 6. ffh = gelu(h @ w_fc1 + b_fc1)   (128x128 BK=32, 1024 blocks)
  gemm_mfma_bk32<1, bf16><<<1024, 256, 0, stream>>>(
      h, wt_fc1, b_fc1, ffh, ROWS, FFDIM, D_MODEL, 32);
  // 7. out = x1 + ffh @ w_fc2 + b_fc2   (64x64 tiles, 1024 blocks)
  gemm_mfma64<true, float><<<1024, 256, 0, stream>>>(
      ffh, wt_fc2, b_fc2, x1, out, ROWS, D_MODEL, FFDIM, 16);
}